// Round 1
// baseline (230.456 us; speedup 1.0000x reference)
//
#include <hip/hip_runtime.h>

// Haar 3-level DWT, fully fused.
// x: [B=2048, L=16384] fp32
// out: concat(cA3[B,2048], cD3[B,2048], cD2[B,4096], cD1[B,8192]) fp32
//
// Each thread handles 8 consecutive inputs of one row:
//   level1: 4 (a,d) pairs; level2: 2 pairs from the a's; level3: 1 pair.
// Writes: cD1 as float4, cD2 as float2, cD3/cA3 scalar -- all coalesced.

#define HS 0.7071067811865476f

constexpr int B = 2048;
constexpr int L = 16384;
constexpr int GROUPS_PER_ROW = L / 8;        // 2048 threads-worth per row
constexpr int TOTAL_UNITS = B * GROUPS_PER_ROW; // 4,194,304

__global__ __launch_bounds__(256) void haar3_kernel(const float* __restrict__ x,
                                                    float* __restrict__ out) {
    const int u = blockIdx.x * 256 + threadIdx.x;     // [0, TOTAL_UNITS)
    const int row = u >> 11;                           // u / 2048
    const int pos = u & 2047;                          // group-of-8 index in row

    const float4* xin = (const float4*)(x + ((size_t)row << 14) + ((size_t)pos << 3));
    const float4 v0 = xin[0];
    const float4 v1 = xin[1];

    // level 1
    const float a10 = HS * (v0.x + v0.y), d10 = HS * (v0.x - v0.y);
    const float a11 = HS * (v0.z + v0.w), d11 = HS * (v0.z - v0.w);
    const float a12 = HS * (v1.x + v1.y), d12 = HS * (v1.x - v1.y);
    const float a13 = HS * (v1.z + v1.w), d13 = HS * (v1.z - v1.w);
    // level 2
    const float a20 = HS * (a10 + a11), d20 = HS * (a10 - a11);
    const float a21 = HS * (a12 + a13), d21 = HS * (a12 - a13);
    // level 3
    const float a3 = HS * (a20 + a21), d3 = HS * (a20 - a21);

    // output section bases (in floats)
    float* cA3 = out;                                  // B*2048
    float* cD3 = out + (size_t)B * 2048;               // B*2048
    float* cD2 = out + (size_t)B * 2048 * 2;           // B*4096
    float* cD1 = out + (size_t)B * 2048 * 2 + (size_t)B * 4096; // B*8192

    const size_t rp = ((size_t)row << 11) + pos;       // row*2048 + pos
    cA3[rp] = a3;
    cD3[rp] = d3;
    ((float2*)cD2)[rp] = make_float2(d20, d21);        // elem offset row*4096 + pos*2
    ((float4*)cD1)[rp] = make_float4(d10, d11, d12, d13); // elem offset row*8192 + pos*4
}

extern "C" void kernel_launch(void* const* d_in, const int* in_sizes, int n_in,
                              void* d_out, int out_size, void* d_ws, size_t ws_size,
                              hipStream_t stream) {
    const float* x = (const float*)d_in[0];
    float* out = (float*)d_out;
    constexpr int block = 256;
    constexpr int grid = TOTAL_UNITS / block;          // 16384 blocks
    haar3_kernel<<<grid, block, 0, stream>>>(x, out);
}

// Round 2
// 215.972 us; speedup vs baseline: 1.0671x; 1.0671x over previous
//
#include <hip/hip_runtime.h>

// Haar 3-level DWT, fully fused, one float4 per thread.
// x: [B=2048, L=16384] fp32
// out: concat(cA3[B,2048], cD3[B,2048], cD2[B,4096], cD1[B,8192]) fp32
//
// Thread u owns x[4u..4u+3] (one perfectly-coalesced 16B load):
//   level1: 2 (a,d) pairs -> cD1 float2 store
//   level2: 1 (a,d) pair  -> cD2 scalar store
//   level3: exchange a2 with lane^1 via shuffle; even lanes store cA3/cD3
// All loads/stores non-temporal (stream-once data, keep L2 free).

#define HS 0.7071067811865476f

typedef float vf4 __attribute__((ext_vector_type(4)));
typedef float vf2 __attribute__((ext_vector_type(2)));

constexpr int B = 2048;
constexpr int L = 16384;
constexpr int UNITS = B * (L / 4);            // 8,388,608 float4 units
constexpr size_t OFF_CD3 = (size_t)B * 2048;  //  4,194,304
constexpr size_t OFF_CD2 = OFF_CD3 * 2;       //  8,388,608
constexpr size_t OFF_CD1 = OFF_CD2 + (size_t)B * 4096; // 16,777,216

__global__ __launch_bounds__(256) void haar3_kernel(const vf4* __restrict__ x4,
                                                    float* __restrict__ out) {
    const int u = blockIdx.x * 256 + threadIdx.x;   // float4 index, = row*4096 + pos
    const int pos = u & 4095;

    const vf4 v = __builtin_nontemporal_load(&x4[u]);

    // level 1
    const float a10 = HS * (v.x + v.y), d10 = HS * (v.x - v.y);
    const float a11 = HS * (v.z + v.w), d11 = HS * (v.z - v.w);
    // level 2
    const float a2 = HS * (a10 + a11), d2 = HS * (a10 - a11);

    // cD1: row*8192 + pos*4 .. +1  ->  float2 index u (8B/lane, coalesced)
    vf2 d1v; d1v.x = d10; d1v.y = d11;
    __builtin_nontemporal_store(d1v, ((vf2*)(out + OFF_CD1)) + u);
    // cD2: row*4096 + pos = u (4B/lane, coalesced)
    __builtin_nontemporal_store(d2, out + OFF_CD2 + u);

    // level 3: partner a2 from lane^1 (pos parity == lane parity)
    const float a2p = __shfl_xor(a2, 1);
    if ((pos & 1) == 0) {
        const int rp3 = u >> 1;                     // row*2048 + pos/2
        __builtin_nontemporal_store(HS * (a2 + a2p), out + rp3);            // cA3
        __builtin_nontemporal_store(HS * (a2 - a2p), out + OFF_CD3 + rp3);  // cD3
    }
}

extern "C" void kernel_launch(void* const* d_in, const int* in_sizes, int n_in,
                              void* d_out, int out_size, void* d_ws, size_t ws_size,
                              hipStream_t stream) {
    const vf4* x4 = (const vf4*)d_in[0];
    float* out = (float*)d_out;
    constexpr int block = 256;
    constexpr int grid = UNITS / block;             // 32768 blocks
    haar3_kernel<<<grid, block, 0, stream>>>(x4, out);
}